// Round 3
// baseline (1788.836 us; speedup 1.0000x reference)
//
#include <hip/hip_runtime.h>

// Receptor LSTM on MI355X — two-kernel plan, adaptive workspace. f32 OUTPUT.
//  K1 krnl_xgemm: xpart = x@W_ih^T + (b_ih+b_hh), bf16, pre-packed in the exact
//     MFMA C-fragment layout K2 consumes. Ring-buffered in d_ws (phased if small).
//  K2 krnl_rec: truncated-history parallel LSTM. Per phase: 256 WGs = 8 batch-
//     groups x 32 chunk-groups; each warms up <=4 chunks from zero state
//     (residual 0.5/chunk + forget-gate contraction => truncation ~<1e-3 rel)
//     then emits E chunks. W_hh resident: 46 frags/wave VGPR + 18 frags/wave LDS.
//     Emits raw h straight into d_out ([b][j][ch] float32).
//  K3 stats / K4 normalize: training-mode BatchNorm over [131072,256], in-place f32.
// ws layout: [stats 4 KB][xfrag ring (32E+4) MB], E picked from ws_size.

typedef __attribute__((ext_vector_type(8))) short short8;
typedef __attribute__((ext_vector_type(4))) float floatx4;
typedef __attribute__((ext_vector_type(2))) unsigned int uintx2;
typedef __attribute__((ext_vector_type(4))) unsigned int uintx4;

#define S_LEN   4096
#define NCHUNK  1024
#define WARM_T  4

__device__ __forceinline__ unsigned short f2bf(float f){
  unsigned u = __builtin_bit_cast(unsigned, f);
  u += 0x7FFFu + ((u >> 16) & 1u);
  return (unsigned short)(u >> 16);
}
__device__ __forceinline__ float bf2f(unsigned short h){
  unsigned u = ((unsigned)h) << 16;
  return __builtin_bit_cast(float, u);
}
__device__ __forceinline__ unsigned pack2(unsigned short a, unsigned short b){
  return (unsigned)a | ((unsigned)b << 16);
}
__device__ __forceinline__ float fsig(float x){
  return __builtin_amdgcn_rcpf(1.f + __expf(-x));
}
__device__ __forceinline__ float ftanh(float x){
  return 2.f * __builtin_amdgcn_rcpf(1.f + __expf(-2.f * x)) - 1.f;
}

// ---------------------------------------------------------------------------
// K1: xpart GEMM. grid = 8 bg * ntiles (64 timesteps each), block 512 (8 waves).
// Wave w owns hidden channels [32w,32w+32): frag f = type*2+sub,
// n = type*256 + w*32 + sub*16 + cl.
// Output frag layout: [t_local][bg][w][lane][32 shorts] (64 B/lane contiguous).
// ---------------------------------------------------------------------------
__global__ __launch_bounds__(512, 2) void krnl_xgemm(
    const float* __restrict__ x, const float* __restrict__ Wih,
    const float* __restrict__ bih, const float* __restrict__ bhh,
    unsigned short* __restrict__ xfrag, int tbase, int tcount)
{
  __shared__ unsigned short xlds[16 * 136];
  const int tid = threadIdx.x;
  const int w = tid >> 6, lane = tid & 63;
  const int cl = lane & 15, quad = lane >> 4;
  const int bg = blockIdx.x & 7, tslice = blockIdx.x >> 3;

  short8 Bw[32];
  float bias[8];
#pragma unroll
  for (int f = 0; f < 8; ++f) {
    const int type = f >> 1, sub = f & 1;
    const int n = type * 256 + w * 32 + sub * 16 + cl;
    bias[f] = bih[n] + bhh[n];
#pragma unroll
    for (int kt = 0; kt < 4; ++kt) {
      const float* src = Wih + n * 128 + kt * 32 + quad * 8;
      floatx4 a0 = *(const floatx4*)(src);
      floatx4 a1 = *(const floatx4*)(src + 4);
      uintx4 u;
      u.x = pack2(f2bf(a0.x), f2bf(a0.y));
      u.y = pack2(f2bf(a0.z), f2bf(a0.w));
      u.z = pack2(f2bf(a1.x), f2bf(a1.y));
      u.w = pack2(f2bf(a1.z), f2bf(a1.w));
      Bw[kt * 8 + f] = __builtin_bit_cast(short8, u);
    }
  }

  const int row = tid >> 5, c4 = (tid & 31) * 4;
  const float* xsrc = x + ((size_t)(bg * 16 + row) * S_LEN) * 128 + c4;

  int tl_end = tslice * 64 + 64;
  if (tl_end > tcount) tl_end = tcount;
  for (int tl = tslice * 64; tl < tl_end; ++tl) {
    const int t = tbase + tl;
    floatx4 v = *(const floatx4*)(xsrc + (size_t)t * 128);
    uintx2 xv;
    xv.x = pack2(f2bf(v.x), f2bf(v.y));
    xv.y = pack2(f2bf(v.z), f2bf(v.w));
    *(uintx2*)(xlds + row * 136 + c4) = xv;
    __syncthreads();

    floatx4 acc[8];
    const unsigned short* hA = xlds + cl * 136 + quad * 8;
#pragma unroll
    for (int kt = 0; kt < 4; ++kt) {
      short8 a = *(const short8*)(hA + kt * 32);
#pragma unroll
      for (int f = 0; f < 8; ++f) {
        if (kt == 0) {
          floatx4 z; z.x = 0.f; z.y = 0.f; z.z = 0.f; z.w = 0.f;
          acc[f] = __builtin_amdgcn_mfma_f32_16x16x32_bf16(a, Bw[kt*8+f], z, 0, 0, 0);
        } else {
          acc[f] = __builtin_amdgcn_mfma_f32_16x16x32_bf16(a, Bw[kt*8+f], acc[f], 0, 0, 0);
        }
      }
    }

    unsigned short* dst = xfrag + ((((size_t)tl * 8 + bg) * 8 + w) * 64 + lane) * 32;
#pragma unroll
    for (int p = 0; p < 4; ++p) {
      const int f0 = p * 2, f1 = p * 2 + 1;
      uintx4 o;
      o.x = pack2(f2bf(acc[f0].x + bias[f0]), f2bf(acc[f0].y + bias[f0]));
      o.y = pack2(f2bf(acc[f0].z + bias[f0]), f2bf(acc[f0].w + bias[f0]));
      o.z = pack2(f2bf(acc[f1].x + bias[f1]), f2bf(acc[f1].y + bias[f1]));
      o.w = pack2(f2bf(acc[f1].z + bias[f1]), f2bf(acc[f1].w + bias[f1]));
      *(uintx4*)(dst + p * 8) = o;
    }
    __syncthreads();
  }
}

// ---------------------------------------------------------------------------
// K2: recurrent kernel. grid 256 = bg(8) x jg_local(32), block 512 (8 waves).
// Static LDS: per-wave W_hh frag ids 0..17 (9216 shorts/wave), then h[16][264].
// Emits raw f32 h into d_out [b][j][ch].
// ---------------------------------------------------------------------------
__global__ __launch_bounds__(512, 2) void krnl_rec(
    const float* __restrict__ Whh,
    const unsigned short* __restrict__ xfrag,
    float* __restrict__ out,
    int tbase, int jg0, int E)
{
  __shared__ unsigned short lds[77952];   // 155904 B < 160 KiB
  const int tid = threadIdx.x;
  const int w = tid >> 6, lane = tid & 63;
  const int cl = lane & 15, quad = lane >> 4;
  const int bg = blockIdx.x & 7;
  const int jg = jg0 + (blockIdx.x >> 3);
  const int js_emit = jg * E;
  int js = js_emit - WARM_T; if (js < 0) js = 0;
  const int warm_steps = (js_emit - js) * 4;
  const int nsteps = warm_steps + E * 4;

  unsigned short* Wlds = lds + w * (18 * 512);
  unsigned short* hlds = lds + 8 * 18 * 512;   // short offset 73728

  short8 Wreg[46];
#pragma unroll
  for (int kt = 0; kt < 8; ++kt) {
#pragma unroll
    for (int f = 0; f < 8; ++f) {
      const int type = f >> 1, sub = f & 1;
      const int n = type * 256 + w * 32 + sub * 16 + cl;
      const float* src = Whh + n * 256 + kt * 32 + quad * 8;
      floatx4 a0 = *(const floatx4*)(src);
      floatx4 a1 = *(const floatx4*)(src + 4);
      uintx4 u;
      u.x = pack2(f2bf(a0.x), f2bf(a0.y));
      u.y = pack2(f2bf(a0.z), f2bf(a0.w));
      u.z = pack2(f2bf(a1.x), f2bf(a1.y));
      u.w = pack2(f2bf(a1.z), f2bf(a1.w));
      const int id = kt * 8 + f;
      if (id < 18) {
        *(uintx4*)(Wlds + id * 512 + lane * 8) = u;
      } else {
        Wreg[id - 18] = __builtin_bit_cast(short8, u);
      }
    }
  }
  for (int i = tid; i < 2112; i += 512) ((unsigned*)(hlds))[i] = 0u;
  float cst[8];
#pragma unroll
  for (int i = 0; i < 8; ++i) cst[i] = 0.f;
  __syncthreads();

  const int tl0 = js * 4 - tbase;   // >= 0 by construction
  const unsigned short* xptr =
      xfrag + (((size_t)tl0 * 8 + bg) * 8 + w) * 2048 + lane * 32;
  const unsigned short* hA = hlds + cl * 264 + quad * 8;

  for (int s = 0; s < nsteps; ++s) {
    uintx4 xs0 = *(const uintx4*)(xptr);
    uintx4 xs1 = *(const uintx4*)(xptr + 8);
    uintx4 xs2 = *(const uintx4*)(xptr + 16);
    uintx4 xs3 = *(const uintx4*)(xptr + 24);

    floatx4 acc[8];
#pragma unroll
    for (int kt = 0; kt < 8; ++kt) {
      short8 a = *(const short8*)(hA + kt * 32);
#pragma unroll
      for (int f = 0; f < 8; ++f) {
        const int id = kt * 8 + f;
        short8 b;
        if (id < 18) b = *(const short8*)(Wlds + id * 512 + lane * 8);
        else         b = Wreg[id - 18];
        if (kt == 0) {
          floatx4 z; z.x = 0.f; z.y = 0.f; z.z = 0.f; z.w = 0.f;
          acc[f] = __builtin_amdgcn_mfma_f32_16x16x32_bf16(a, b, z, 0, 0, 0);
        } else {
          acc[f] = __builtin_amdgcn_mfma_f32_16x16x32_bf16(a, b, acc[f], 0, 0, 0);
        }
      }
    }
    __syncthreads();   // all A-reads of hlds done before overwrite

    unsigned xd[16];
    xd[0]  = xs0.x; xd[1]  = xs0.y; xd[2]  = xs0.z; xd[3]  = xs0.w;
    xd[4]  = xs1.x; xd[5]  = xs1.y; xd[6]  = xs1.z; xd[7]  = xs1.w;
    xd[8]  = xs2.x; xd[9]  = xs2.y; xd[10] = xs2.z; xd[11] = xs2.w;
    xd[12] = xs3.x; xd[13] = xs3.y; xd[14] = xs3.z; xd[15] = xs3.w;

    const bool lastst = (s & 3) == 3;
    const bool emit = lastst && (s >= warm_steps);
    const float scale = lastst ? 0.5f : 1.f;
    const int j = js + (s >> 2);

#pragma unroll
    for (int sub = 0; sub < 2; ++sub) {
      float hr[4];
      const int fi = 0 + sub, ff = 2 + sub, fg = 4 + sub, fo = 6 + sub;
#pragma unroll
      for (int r = 0; r < 4; ++r) {
        const int dsel = r >> 1, hsel = (r & 1) * 16;
        float xi = bf2f((unsigned short)((xd[fi * 2 + dsel] >> hsel) & 0xFFFF));
        float xf = bf2f((unsigned short)((xd[ff * 2 + dsel] >> hsel) & 0xFFFF));
        float xg = bf2f((unsigned short)((xd[fg * 2 + dsel] >> hsel) & 0xFFFF));
        float xo = bf2f((unsigned short)((xd[fo * 2 + dsel] >> hsel) & 0xFFFF));
        float vi = acc[fi][r] + xi;
        float vf = acc[ff][r] + xf;
        float vg = acc[fg][r] + xg;
        float vo = acc[fo][r] + xo;
        float si = fsig(vi), sf = fsig(vf), so = fsig(vo);
        float tg = ftanh(vg);
        float cn = sf * cst[sub * 4 + r] + si * tg;
        float hn = so * ftanh(cn);
        cst[sub * 4 + r] = cn * scale;
        hr[r] = hn;
        hlds[(quad * 4 + r) * 264 + w * 32 + sub * 16 + cl] = f2bf(hn * scale);
      }
      if (emit) {
        const int ch = w * 32 + sub * 16 + cl;
#pragma unroll
        for (int r = 0; r < 4; ++r) {
          const int b = bg * 16 + quad * 4 + r;
          out[(size_t)b * (NCHUNK * 256) + (size_t)j * 256 + ch] = hr[r];
        }
      }
    }
    __syncthreads();   // h writes visible before next step's A-reads
    xptr += 131072;    // one timestep: 8 bg * 8 w * 64 lanes * 32 shorts
  }
}

// ---------------------------------------------------------------------------
// K3/K4: BatchNorm (biased batch stats) over d_out [b][j][ch] f32, then
// in-place normalize. stats[0..255]=sum, [256..511]=sumsq.
// ---------------------------------------------------------------------------
__global__ void krnl_zero(float* __restrict__ stats){ stats[threadIdx.x] = 0.f; }

__global__ __launch_bounds__(256, 4) void krnl_stats(
    const float* __restrict__ out, float* __restrict__ stats)
{
  __shared__ float lsum[4][256];
  __shared__ float lsq[4][256];
  const int tid = threadIdx.x;
  const int brow = tid >> 6, c4 = (tid & 63) * 4;
  float s0=0.f,s1=0.f,s2=0.f,s3=0.f, q0=0.f,q1=0.f,q2=0.f,q3=0.f;
  for (int jj = 0; jj < 8; ++jj) {
    const int j = blockIdx.x * 8 + jj;
    for (int b = brow; b < 128; b += 4) {
      floatx4 v = *(const floatx4*)(out + ((size_t)b * NCHUNK + j) * 256 + c4);
      s0 += v.x; s1 += v.y; s2 += v.z; s3 += v.w;
      q0 += v.x*v.x; q1 += v.y*v.y; q2 += v.z*v.z; q3 += v.w*v.w;
    }
  }
  lsum[brow][c4+0] = s0; lsum[brow][c4+1] = s1;
  lsum[brow][c4+2] = s2; lsum[brow][c4+3] = s3;
  lsq[brow][c4+0] = q0; lsq[brow][c4+1] = q1;
  lsq[brow][c4+2] = q2; lsq[brow][c4+3] = q3;
  __syncthreads();
  float ts = 0.f, tq = 0.f;
#pragma unroll
  for (int br = 0; br < 4; ++br) { ts += lsum[br][tid]; tq += lsq[br][tid]; }
  atomicAdd(&stats[tid], ts);
  atomicAdd(&stats[256 + tid], tq);
}

__global__ __launch_bounds__(256, 4) void krnl_norm(
    float* __restrict__ out, const float* __restrict__ stats,
    const float* __restrict__ gamma, const float* __restrict__ beta)
{
  const int tid = threadIdx.x;
  const int rl = tid >> 6, c4 = (tid & 63) * 4;
  const float inv = 1.f / 131072.f;
  float sc[4], sh[4];
#pragma unroll
  for (int k = 0; k < 4; ++k) {
    const int c = c4 + k;
    const float mean = stats[c] * inv;
    const float var = stats[256 + c] * inv - mean * mean;
    const float s = rsqrtf(var + 1e-5f) * gamma[c];
    sc[k] = s; sh[k] = beta[c] - mean * s;
  }
  for (int it = 0; it < 16; ++it) {
    const size_t r = (size_t)blockIdx.x * 64 + it * 4 + rl;
    float* p = out + r * 256 + c4;
    floatx4 v = *(const floatx4*)(p);
    floatx4 o;
    o.x = v.x * sc[0] + sh[0];
    o.y = v.y * sc[1] + sh[1];
    o.z = v.z * sc[2] + sh[2];
    o.w = v.w * sc[3] + sh[3];
    *(floatx4*)(p) = o;
  }
}

extern "C" void kernel_launch(void* const* d_in, const int* in_sizes, int n_in,
                              void* d_out, int out_size, void* d_ws, size_t ws_size,
                              hipStream_t stream) {
  const float* x     = (const float*)d_in[0];
  const float* Wih   = (const float*)d_in[1];
  const float* Whh   = (const float*)d_in[2];
  const float* bih   = (const float*)d_in[3];
  const float* bhh   = (const float*)d_in[4];
  const float* gamma = (const float*)d_in[5];
  const float* beta  = (const float*)d_in[6];
  float* out = (float*)d_out;

  float* stats = (float*)d_ws;
  unsigned short* xfrag = (unsigned short*)((char*)d_ws + 4096);
  const size_t avail = ws_size > 4096 ? ws_size - 4096 : 0;

  int E = 1;
  if      (avail >= ((size_t)(32 * 32 + 4)) << 20) E = 32;
  else if (avail >= ((size_t)(32 * 16 + 4)) << 20) E = 16;
  else if (avail >= ((size_t)(32 * 8  + 4)) << 20) E = 8;
  else if (avail >= ((size_t)(32 * 4  + 4)) << 20) E = 4;
  else if (avail >= ((size_t)(32 * 2  + 4)) << 20) E = 2;
  const int P = NCHUNK / (32 * E);

  hipLaunchKernelGGL(krnl_zero, dim3(1), dim3(512), 0, stream, stats);
  for (int p = 0; p < P; ++p) {
    const int c0 = p * 32 * E;                       // first emitted chunk
    const int cb = (c0 >= WARM_T) ? c0 - WARM_T : 0; // first buffered chunk
    const int tbase = cb * 4;
    const int tend = (c0 + 32 * E) * 4;
    const int tcount = tend - tbase;
    const int ntiles = (tcount + 63) / 64;
    hipLaunchKernelGGL(krnl_xgemm, dim3(8 * ntiles), dim3(512), 0, stream,
                       x, Wih, bih, bhh, xfrag, tbase, tcount);
    hipLaunchKernelGGL(krnl_rec, dim3(256), dim3(512), 0, stream,
                       Whh, xfrag, out, tbase, p * 32, E);
  }
  hipLaunchKernelGGL(krnl_stats, dim3(128), dim3(256), 0, stream, out, stats);
  hipLaunchKernelGGL(krnl_norm, dim3(2048), dim3(256), 0, stream, out, stats, gamma, beta);
}